// Round 7
// baseline (285.680 us; speedup 1.0000x reference)
//
#include <hip/hip_runtime.h>
#include <hip/hip_bf16.h>

// Problem dims (AttentivePoolingNetwork)
#define BB   128
#define LQ   128
#define LA   512
#define EMBD 300
#define FILT 400
#define KW   3

#define NT   25    // n-tiles of 16 (400)
#define KC   30    // k-chunks of 32 for encode (3 emb-blocks padded to 320 each)
#define KCF  13    // k-chunks of 32 over FILT=400 (12 full + 1 zero-padded)
#define MT   32    // rows per block (encode / gemmT)

typedef unsigned short u16;
typedef unsigned int   u32;
typedef __attribute__((ext_vector_type(4))) int    i32x4;
typedef __attribute__((ext_vector_type(4))) float  f32x4;
typedef __attribute__((ext_vector_type(8))) __bf16 bf16x8;

__device__ __forceinline__ float b2f(u16 h){ return __uint_as_float(((u32)h) << 16); }
__device__ __forceinline__ u16 f2b(float f){
  u32 u = __float_as_uint(f);
  u32 r = (u + 0x7FFFu + ((u >> 16) & 1u)) >> 16;   // RNE
  return (u16)r;
}
__device__ __forceinline__ u32 encf(float f){
  u32 u = __float_as_uint(f);
  return (u & 0x80000000u) ? ~u : (u | 0x80000000u);
}
__device__ __forceinline__ float decf(u32 k){
  u32 u = (k & 0x80000000u) ? (k ^ 0x80000000u) : ~k;
  return __uint_as_float(u);
}
__device__ __forceinline__ bf16x8 bzero(){
  i32x4 z; z.x = 0; z.y = 0; z.z = 0; z.w = 0;
  return __builtin_bit_cast(bf16x8, z);
}

// conv_w [F][E][K] fp32 -> wTf in MFMA B-fragment order:
// wTf[kc][nt][lane][j] (bf16), element = B[k'=kc*32+quad*8+j][n=nt*16+(lane&15)]
// k' -> (kk=k'/320, e=k'%320); value = (e<300) ? conv_w[n][e][kk] : 0.
__global__ void k_wt2(const float* __restrict__ cw, u32* __restrict__ wTf){
  int idx = blockIdx.x * 256 + threadIdx.x;
  if (idx >= KC * NT * 64) return;
  int kc  = idx / (NT * 64);
  int rem = idx - kc * (NT * 64);
  int nt  = rem >> 6;
  int lane = rem & 63;
  int n = nt * 16 + (lane & 15);
  int quad = lane >> 4;
  u32 pack[4];
  #pragma unroll
  for (int d = 0; d < 4; d++){
    u16 h[2];
    #pragma unroll
    for (int s = 0; s < 2; s++){
      int kp = kc * 32 + quad * 8 + 2 * d + s;
      int kk = kp / 320, e = kp - kk * 320;
      float v = (e < EMBD) ? cw[(size_t)n * (EMBD * KW) + e * KW + kk] : 0.f;
      h[s] = f2b(v);
    }
    pack[d] = (u32)h[0] | ((u32)h[1] << 16);
  }
  i32x4 out4; out4.x = pack[0]; out4.y = pack[1]; out4.z = pack[2]; out4.w = pack[3];
  *((i32x4*)wTf + idx) = out4;
}

// W [f][g] fp32 -> wF B-fragment order (zero for f>=400).
__global__ void k_wf(const float* __restrict__ W, u32* __restrict__ wF){
  int idx = blockIdx.x * 256 + threadIdx.x;
  if (idx >= KCF * NT * 64) return;
  int kc  = idx / (NT * 64);
  int rem = idx - kc * (NT * 64);
  int nt  = rem >> 6;
  int lane = rem & 63;
  int n = nt * 16 + (lane & 15);
  int quad = lane >> 4;
  u32 pack[4];
  #pragma unroll
  for (int d = 0; d < 4; d++){
    u16 h[2];
    #pragma unroll
    for (int s = 0; s < 2; s++){
      int k = kc * 32 + quad * 8 + 2 * d + s;
      float v = (k < FILT) ? W[(size_t)k * FILT + n] : 0.f;
      h[s] = f2b(v);
    }
    pack[d] = (u32)h[0] | ((u32)h[1] << 16);
  }
  i32x4 out4; out4.x = pack[0]; out4.y = pack[1]; out4.z = pack[2]; out4.w = pack[3];
  *((i32x4*)wF + idx) = out4;
}

// Embed + conv1d(pad=1) as MFMA GEMM, 32 rows x 200-col half per block.
// grid ((B*L)/32, 2). Wave w: nt = base+w+4j, j<3 (+ j=3 for half 0 wave 0).
// A (gathered emb rows) staged in LDS; BOTH A (ds_read) and B (global) are
// 1-deep register-prefetched so each kc's waits overlap the prior kc's MFMAs.
__global__ __launch_bounds__(256) void k_encode_mfma(const int* __restrict__ toks,
    const float* __restrict__ emb, const u32* __restrict__ wTf,
    const float* __restrict__ bias, u16* __restrict__ out, int L){
  __shared__ u16 At[34 * 328];   // 32+2 halo rows, stride 328

  const int tid  = threadIdx.x;
  const int w    = tid >> 6;
  const int lane = tid & 63;
  const int col  = lane & 15;
  const int quad = lane >> 4;
  const int half = blockIdx.y;
  const int base_nt = half ? 13 : 0;
  const bool has4 = (half == 0) && (w == 0);   // wave-uniform
  const int row0 = blockIdx.x * MT;
  const int b    = row0 / L;
  const int l0   = row0 - b * L;

  for (int i = tid; i < 34 * 328 / 2; i += 256) ((u32*)At)[i] = 0u;
  __syncthreads();
  for (int i = tid; i < 34 * 75; i += 256){
    int r = i / 75, c4 = i - r * 75;
    int pos = l0 - 1 + r;
    if ((unsigned)pos < (unsigned)L){
      int t = toks[b * L + pos];
      float4 v = *((const float4*)(emb + (size_t)t * EMBD) + c4);
      u32 p0 = (u32)f2b(v.x) | ((u32)f2b(v.y) << 16);
      u32 p1 = (u32)f2b(v.z) | ((u32)f2b(v.w) << 16);
      int di = (r * 328 + c4 * 4) >> 1;
      ((u32*)At)[di]     = p0;
      ((u32*)At)[di + 1] = p1;
    }
  }

  f32x4 acc[4][2];
  #pragma unroll
  for (int j = 0; j < 4; j++)
    #pragma unroll
    for (int mf = 0; mf < 2; mf++)
      acc[j][mf] = (f32x4){0.f, 0.f, 0.f, 0.f};

  __syncthreads();

  const i32x4* bbase = (const i32x4*)wTf + (size_t)(base_nt + w) * 64 + lane;
  i32x4 Bb[2][4];
  i32x4 Ab[2][2];
  {
    #pragma unroll
    for (int j = 0; j < 3; j++) Bb[0][j] = bbase[(4 * j) * 64];
    if (has4) Bb[0][3] = bbase[12 * 64];
    const int ebase0 = quad * 8;                 // kc=0: kk=0, e0=0
    Ab[0][0] = *(const i32x4*)(At + (col) * 328 + ebase0);
    Ab[0][1] = *(const i32x4*)(At + (16 + col) * 328 + ebase0);
  }
  #pragma unroll
  for (int kc = 0; kc < KC; kc++){
    const int cur = kc & 1;
    if (kc + 1 < KC){
      const i32x4* s = bbase + (size_t)(kc + 1) * (NT * 64);
      #pragma unroll
      for (int j = 0; j < 3; j++) Bb[cur ^ 1][j] = s[(4 * j) * 64];
      if (has4) Bb[cur ^ 1][3] = s[12 * 64];
      const int kk1 = (kc + 1) / 10, e01 = ((kc + 1) - kk1 * 10) * 32;
      const int ebase1 = e01 + quad * 8;
      Ab[cur ^ 1][0] = *(const i32x4*)(At + (col + kk1) * 328 + ebase1);
      Ab[cur ^ 1][1] = *(const i32x4*)(At + (16 + col + kk1) * 328 + ebase1);
    }
    bf16x8 a0 = __builtin_bit_cast(bf16x8, Ab[cur][0]);
    bf16x8 a1 = __builtin_bit_cast(bf16x8, Ab[cur][1]);
    #pragma unroll
    for (int j = 0; j < 3; j++){
      bf16x8 bf = __builtin_bit_cast(bf16x8, Bb[cur][j]);
      acc[j][0] = __builtin_amdgcn_mfma_f32_16x16x32_bf16(a0, bf, acc[j][0], 0, 0, 0);
      acc[j][1] = __builtin_amdgcn_mfma_f32_16x16x32_bf16(a1, bf, acc[j][1], 0, 0, 0);
    }
    if (has4){
      bf16x8 bf = __builtin_bit_cast(bf16x8, Bb[cur][3]);
      acc[3][0] = __builtin_amdgcn_mfma_f32_16x16x32_bf16(a0, bf, acc[3][0], 0, 0, 0);
      acc[3][1] = __builtin_amdgcn_mfma_f32_16x16x32_bf16(a1, bf, acc[3][1], 0, 0, 0);
    }
  }

  // epilogue: + bias, bf16 store. C/D: col=lane&15, row=quad*4+reg.
  #pragma unroll
  for (int j = 0; j < 4; j++){
    if (j == 3 && !has4) continue;     // wave-uniform
    int n = (base_nt + w + 4 * j) * 16 + col;
    float bv = bias[n];
    #pragma unroll
    for (int mf = 0; mf < 2; mf++){
      int rbase = row0 + mf * 16 + quad * 4;
      #pragma unroll
      for (int r = 0; r < 4; r++)
        out[(size_t)(rbase + r) * FILT + n] = f2b(acc[j][mf][r] + bv);
    }
  }
}

// T = QT * W, MFMA, no LDS, reg-double-buffered A and B, N-split in 2 halves.
// grid (BB*LQ/32, 2). Wave w: nt = base+w+4j, j<3 (+ nt=12 for half0 wave0).
__global__ __launch_bounds__(256) void k_gemmT3(const u16* __restrict__ QT,
    const u32* __restrict__ wF, u16* __restrict__ T){
  const int tid  = threadIdx.x;
  const int w    = tid >> 6;
  const int lane = tid & 63;
  const int col  = lane & 15;
  const int quad = lane >> 4;
  const int half = blockIdx.y;
  const int base_nt = half ? 13 : 0;
  const bool has4 = (half == 0) && (w == 0);
  const int row0 = blockIdx.x * MT;

  f32x4 acc[4][2];
  #pragma unroll
  for (int j = 0; j < 4; j++)
    #pragma unroll
    for (int mf = 0; mf < 2; mf++)
      acc[j][mf] = (f32x4){0.f, 0.f, 0.f, 0.f};

  const u16* arow0 = QT + (size_t)(row0 + col) * FILT;
  const u16* arow1 = QT + (size_t)(row0 + 16 + col) * FILT;
  const i32x4* bbase = (const i32x4*)wF + (size_t)(base_nt + w) * 64 + lane;

  i32x4 Ab[2][2];
  i32x4 Bb[2][4];
  {
    int off = quad * 8;
    Ab[0][0] = *(const i32x4*)(arow0 + off);
    Ab[0][1] = *(const i32x4*)(arow1 + off);
    #pragma unroll
    for (int j = 0; j < 3; j++) Bb[0][j] = bbase[(4 * j) * 64];
    if (has4) Bb[0][3] = bbase[12 * 64];
  }
  #pragma unroll
  for (int kc = 0; kc < KCF; kc++){
    const int cur = kc & 1;
    if (kc + 1 < KCF){
      int off = (kc + 1) * 32 + quad * 8;
      Ab[cur ^ 1][0] = *(const i32x4*)(arow0 + off);
      Ab[cur ^ 1][1] = *(const i32x4*)(arow1 + off);
      const i32x4* s = bbase + (size_t)(kc + 1) * (NT * 64);
      #pragma unroll
      for (int j = 0; j < 3; j++) Bb[cur ^ 1][j] = s[(4 * j) * 64];
      if (has4) Bb[cur ^ 1][3] = s[12 * 64];
    }
    bf16x8 a0 = __builtin_bit_cast(bf16x8, Ab[cur][0]);
    bf16x8 a1 = __builtin_bit_cast(bf16x8, Ab[cur][1]);
    #pragma unroll
    for (int j = 0; j < 3; j++){
      bf16x8 bf = __builtin_bit_cast(bf16x8, Bb[cur][j]);
      acc[j][0] = __builtin_amdgcn_mfma_f32_16x16x32_bf16(a0, bf, acc[j][0], 0, 0, 0);
      acc[j][1] = __builtin_amdgcn_mfma_f32_16x16x32_bf16(a1, bf, acc[j][1], 0, 0, 0);
    }
    if (has4){
      bf16x8 bf = __builtin_bit_cast(bf16x8, Bb[cur][3]);
      acc[3][0] = __builtin_amdgcn_mfma_f32_16x16x32_bf16(a0, bf, acc[3][0], 0, 0, 0);
      acc[3][1] = __builtin_amdgcn_mfma_f32_16x16x32_bf16(a1, bf, acc[3][1], 0, 0, 0);
    }
  }

  #pragma unroll
  for (int j = 0; j < 4; j++){
    if (j == 3 && !has4) continue;
    int n = (base_nt + w + 4 * j) * 16 + col;
    #pragma unroll
    for (int mf = 0; mf < 2; mf++){
      int rbase = row0 + mf * 16 + quad * 4;
      #pragma unroll
      for (int r = 0; r < 4; r++)
        T[(size_t)(rbase + r) * FILT + n] = f2b(acc[j][mf][r]);
    }
  }
}

// Scores S[q][a] = sum_g T[q][g]*AT[a][g] via MFMA; row/col maxes only.
// grid (LA/128, BB, 2): z selects 64 q-rows; wave w covers q-tile z*4+w, 8 a-tiles.
// Both rowmax and colmax combined via atomicMax on encf-encoded u32.
__global__ __launch_bounds__(256) void k_scores3(const u16* __restrict__ T,
    const u16* __restrict__ AT, u32* __restrict__ rowmaxE, u32* __restrict__ colmaxE){
  __shared__ float rpart[64][17];
  __shared__ float cpart[128][17];
  const int tid  = threadIdx.x;
  const int w    = tid >> 6;
  const int lane = tid & 63;
  const int col  = lane & 15;
  const int quad = lane >> 4;
  const int b    = blockIdx.y;
  const int a0   = blockIdx.x * 128;
  const int qt   = blockIdx.z * 4 + w;   // q-tile 0..7

  f32x4 acc[8];
  #pragma unroll
  for (int j = 0; j < 8; j++) acc[j] = (f32x4){0.f, 0.f, 0.f, 0.f};

  const u16* tr = T  + (size_t)(b * LQ + qt * 16 + col) * FILT;
  const u16* ar = AT + (size_t)(b * LA + a0 + col) * FILT;

  i32x4 Abuf[2], Bbuf[2][8];
  {
    int off = quad * 8;
    Abuf[0] = *(const i32x4*)(tr + off);
    #pragma unroll
    for (int j = 0; j < 8; j++)
      Bbuf[0][j] = *(const i32x4*)(ar + (size_t)(j * 16) * FILT + off);
  }
  #pragma unroll
  for (int kc = 0; kc < KCF; kc++){
    const int cur = kc & 1;
    if (kc + 1 < KCF){
      int off = (kc + 1) * 32 + quad * 8;
      Abuf[cur ^ 1] = *(const i32x4*)(tr + off);
      #pragma unroll
      for (int j = 0; j < 8; j++)
        Bbuf[cur ^ 1][j] = *(const i32x4*)(ar + (size_t)(j * 16) * FILT + off);
    }
    const bool live = (kc < 12) || (quad < 2);
    bf16x8 a0 = live ? __builtin_bit_cast(bf16x8, Abuf[cur]) : bzero();
    #pragma unroll
    for (int j = 0; j < 8; j++){
      bf16x8 bf = __builtin_bit_cast(bf16x8, Bbuf[cur][j]);
      acc[j] = __builtin_amdgcn_mfma_f32_16x16x32_bf16(a0, bf, acc[j], 0, 0, 0);
    }
  }

  // row partials: local row = w*16 + quad*4 + r (global q = z*64 + local)
  #pragma unroll
  for (int r = 0; r < 4; r++){
    float m = acc[0][r];
    #pragma unroll
    for (int j = 1; j < 8; j++) m = fmaxf(m, acc[j][r]);
    rpart[w * 16 + quad * 4 + r][col] = m;
  }
  // col partials: a = j*16 + col, slot = w*4+quad (16 slots cover 64 q-rows)
  #pragma unroll
  for (int j = 0; j < 8; j++){
    float m = acc[j][0];
    #pragma unroll
    for (int r = 1; r < 4; r++) m = fmaxf(m, acc[j][r]);
    cpart[j * 16 + col][w * 4 + quad] = m;
  }
  __syncthreads();
  if (tid < 64){
    float m = rpart[tid][0];
    #pragma unroll
    for (int g = 1; g < 16; g++) m = fmaxf(m, rpart[tid][g]);
    atomicMax(&rowmaxE[b * LQ + blockIdx.z * 64 + tid], encf(m));
  } else if (tid < 192){
    int a = tid - 64;
    float m2 = cpart[a][0];
    #pragma unroll
    for (int g = 1; g < 16; g++) m2 = fmaxf(m2, cpart[a][g]);
    atomicMax(&colmaxE[b * LA + a0 + a], encf(m2));
  }
  if (tid >= 192 && tid < 256){
    int a = tid - 128;
    float m2 = cpart[a][0];
    #pragma unroll
    for (int g = 1; g < 16; g++) m2 = fmaxf(m2, cpart[a][g]);
    atomicMax(&colmaxE[b * LA + a0 + a], encf(m2));
  }
}

// Softmax weights: roq[b][128], roa[b][512] from encoded maxes. Parallel reductions.
__global__ __launch_bounds__(256) void k_soft(const u32* __restrict__ rme,
    const u32* __restrict__ cme, float* __restrict__ roq, float* __restrict__ roa){
  __shared__ float sq[128];
  __shared__ float sa[512];
  __shared__ float red[4];
  int b = blockIdx.x, tid = threadIdx.x;
  if (tid < 128) sq[tid] = tanhf(decf(rme[b * LQ + tid]));
  sa[tid]       = tanhf(decf(cme[b * LA + tid]));
  sa[tid + 256] = tanhf(decf(cme[b * LA + 256 + tid]));
  __syncthreads();
  if (tid < 64){
    float m = fmaxf(sq[tid], sq[tid + 64]);
    #pragma unroll
    for (int off = 32; off; off >>= 1) m = fmaxf(m, __shfl_down(m, off));
    if (tid == 0) red[0] = m;
  } else if (tid < 128){
    int l = tid - 64;
    float m = sa[l];
    #pragma unroll
    for (int i = 1; i < 8; i++) m = fmaxf(m, sa[l + 64 * i]);
    #pragma unroll
    for (int off = 32; off; off >>= 1) m = fmaxf(m, __shfl_down(m, off));
    if (l == 0) red[1] = m;
  }
  __syncthreads();
  float mq = red[0], ma = red[1];
  if (tid < 128) sq[tid] = __expf(sq[tid] - mq);
  sa[tid]       = __expf(sa[tid] - ma);
  sa[tid + 256] = __expf(sa[tid + 256] - ma);
  __syncthreads();
  if (tid < 64){
    float s = sq[tid] + sq[tid + 64];
    #pragma unroll
    for (int off = 32; off; off >>= 1) s += __shfl_down(s, off);
    if (tid == 0) red[2] = s;
  } else if (tid < 128){
    int l = tid - 64;
    float s = 0.f;
    #pragma unroll
    for (int i = 0; i < 8; i++) s += sa[l + 64 * i];
    #pragma unroll
    for (int off = 32; off; off >>= 1) s += __shfl_down(s, off);
    if (l == 0) red[3] = s;
  }
  __syncthreads();
  float iq = 1.f / red[2], ia = 1.f / red[3];
  if (tid < 128) roq[b * LQ + tid] = sq[tid] * iq;
  roa[b * LA + tid]       = sa[tid] * ia;
  roa[b * LA + 256 + tid] = sa[tid + 256] * ia;
}

// Segment-parallel pooling: grid (4, BB). Segment s: q in [32s,..), a in [128s,..).
// Writes fp32 partials rqp/rap [b][4][FILT].
__global__ __launch_bounds__(256) void k_pool(const u16* __restrict__ QT,
    const u16* __restrict__ AT, const float* __restrict__ roq, const float* __restrict__ roa,
    float* __restrict__ rqp, float* __restrict__ rap){
  __shared__ float wq[32];
  __shared__ float wa[128];
  int s = blockIdx.x, b = blockIdx.y, tid = threadIdx.x;
  if (tid < 32) wq[tid] = roq[b * LQ + s * 32 + tid];
  if (tid >= 128 && tid < 256) wa[tid - 128] = roa[b * LA + s * 128 + (tid - 128)];
  __syncthreads();
  if (tid < FILT / 2){
    const u32* qp = (const u32*)(QT + (size_t)(b * LQ + s * 32) * FILT) + tid;
    const u32* ap = (const u32*)(AT + (size_t)(b * LA + s * 128) * FILT) + tid;
    float rq0 = 0.f, rq1 = 0.f, ra0 = 0.f, ra1 = 0.f;
    for (int q = 0; q < 32; q++){
      u32 u = qp[q * (FILT / 2)];
      float wv = wq[q];
      rq0 += __uint_as_float(u << 16) * wv;
      rq1 += __uint_as_float(u & 0xFFFF0000u) * wv;
    }
    for (int a = 0; a < 128; a++){
      u32 u = ap[a * (FILT / 2)];
      float wv = wa[a];
      ra0 += __uint_as_float(u << 16) * wv;
      ra1 += __uint_as_float(u & 0xFFFF0000u) * wv;
    }
    size_t base = ((size_t)b * 4 + s) * FILT + 2 * tid;
    rqp[base] = rq0; rqp[base + 1] = rq1;
    rap[base] = ra0; rap[base + 1] = ra1;
  }
}

// Reduce 4 partials, cosine similarity. grid (BB), 256 threads.
__global__ __launch_bounds__(256) void k_cos(const float* __restrict__ rqp,
    const float* __restrict__ rap, float* __restrict__ outp){
  __shared__ float rd[4], r1[4], r2[4];
  int b = blockIdx.x, tid = threadIdx.x;
  int lane = tid & 63, w = tid >> 6;
  float d = 0.f, n1 = 0.f, n2 = 0.f;
  for (int f = tid; f < FILT; f += 256){
    size_t base = (size_t)b * 4 * FILT + f;
    float rq = rqp[base] + rqp[base + FILT] + rqp[base + 2 * FILT] + rqp[base + 3 * FILT];
    float ra = rap[base] + rap[base + FILT] + rap[base + 2 * FILT] + rap[base + 3 * FILT];
    d += rq * ra; n1 += rq * rq; n2 += ra * ra;
  }
  #pragma unroll
  for (int off = 32; off; off >>= 1){
    d  += __shfl_down(d, off);
    n1 += __shfl_down(n1, off);
    n2 += __shfl_down(n2, off);
  }
  if (lane == 0){ rd[w] = d; r1[w] = n1; r2[w] = n2; }
  __syncthreads();
  if (tid == 0){
    float D  = rd[0] + rd[1] + rd[2] + rd[3];
    float N1 = r1[0] + r1[1] + r1[2] + r1[3];
    float N2 = r2[0] + r2[1] + r2[2] + r2[3];
    outp[b] = D / (fmaxf(sqrtf(N1), 1e-8f) * fmaxf(sqrtf(N2), 1e-8f));
  }
}

extern "C" void kernel_launch(void* const* d_in, const int* in_sizes, int n_in,
                              void* d_out, int out_size, void* d_ws, size_t ws_size,
                              hipStream_t stream){
  const int*   qtok = (const int*)d_in[0];
  const int*   atok = (const int*)d_in[1];
  const float* emb  = (const float*)d_in[2];
  const float* cw   = (const float*)d_in[3];
  const float* cb   = (const float*)d_in[4];
  const float* W    = (const float*)d_in[5];
  float* outp = (float*)d_out;

  char* ws = (char*)d_ws;
  size_t off = 0;
  auto alloc = [&](size_t bytes) -> char* {
    char* p = ws + off;
    off = (off + bytes + 255) & ~(size_t)255;
    return p;
  };
  u32*   wTf = (u32*)alloc((size_t)KC * NT * 64 * 16);   // 768 KB
  u32*   wF  = (u32*)alloc((size_t)KCF * NT * 64 * 16);  // 333 KB
  u16*   QT  = (u16*)alloc((size_t)BB * LQ * FILT * 2);  // 13.1 MB
  u16*   AT  = (u16*)alloc((size_t)BB * LA * FILT * 2);  // 52.4 MB
  u16*   T   = (u16*)alloc((size_t)BB * LQ * FILT * 2);  // 13.1 MB
  u32*   rme = (u32*)alloc((size_t)BB * LQ * 4);
  u32*   cme = (u32*)alloc((size_t)BB * LA * 4);
  float* roq = (float*)alloc((size_t)BB * LQ * 4);
  float* roa = (float*)alloc((size_t)BB * LA * 4);
  float* rqp = (float*)alloc((size_t)BB * 4 * FILT * 4); // 819 KB
  float* rap = (float*)alloc((size_t)BB * 4 * FILT * 4); // 819 KB

  hipMemsetAsync(rme, 0, (size_t)BB * LQ * 4, stream);   // < encf(any finite)
  hipMemsetAsync(cme, 0, (size_t)BB * LA * 4, stream);

  k_wt2<<<dim3((KC * NT * 64 + 255) / 256), 256, 0, stream>>>(cw, wTf);
  k_wf<<<dim3((KCF * NT * 64 + 255) / 256), 256, 0, stream>>>(W, wF);
  k_encode_mfma<<<dim3(BB * LQ / MT, 2), 256, 0, stream>>>(qtok, emb, wTf, cb, QT, LQ);
  k_encode_mfma<<<dim3(BB * LA / MT, 2), 256, 0, stream>>>(atok, emb, wTf, cb, AT, LA);
  k_gemmT3<<<dim3(BB * LQ / MT, 2), 256, 0, stream>>>(QT, wF, T);
  k_scores3<<<dim3(LA / 128, BB, 2), 256, 0, stream>>>(T, AT, rme, cme);
  k_soft<<<dim3(BB), 256, 0, stream>>>(rme, cme, roq, roa);
  k_pool<<<dim3(4, BB), 256, 0, stream>>>(QT, AT, roq, roa, rqp, rap);
  k_cos<<<dim3(BB), 256, 0, stream>>>(rqp, rap, outp);
}

// Round 8
// 265.426 us; speedup vs baseline: 1.0763x; 1.0763x over previous
//
#include <hip/hip_runtime.h>
#include <hip/hip_bf16.h>

// Problem dims (AttentivePoolingNetwork)
#define BB   128
#define LQ   128
#define LA   512
#define EMBD 300
#define FILT 400
#define KW   3

#define NT   25    // n-tiles of 16 (400)
#define KC   30    // k-chunks of 32 for encode (3 emb-blocks padded to 320 each)
#define KCF  13    // k-chunks of 32 over FILT=400 (12 full + 1 zero-padded)
#define MT   32    // rows per block (encode / gemmT)

typedef unsigned short u16;
typedef unsigned int   u32;
typedef __attribute__((ext_vector_type(4))) int    i32x4;
typedef __attribute__((ext_vector_type(4))) float  f32x4;
typedef __attribute__((ext_vector_type(8))) __bf16 bf16x8;

__device__ __forceinline__ float b2f(u16 h){ return __uint_as_float(((u32)h) << 16); }
__device__ __forceinline__ u16 f2b(float f){
  u32 u = __float_as_uint(f);
  u32 r = (u + 0x7FFFu + ((u >> 16) & 1u)) >> 16;   // RNE
  return (u16)r;
}
__device__ __forceinline__ u32 encf(float f){
  u32 u = __float_as_uint(f);
  return (u & 0x80000000u) ? ~u : (u | 0x80000000u);
}
__device__ __forceinline__ float decf(u32 k){
  u32 u = (k & 0x80000000u) ? (k ^ 0x80000000u) : ~k;
  return __uint_as_float(u);
}
__device__ __forceinline__ bf16x8 bzero(){
  i32x4 z; z.x = 0; z.y = 0; z.z = 0; z.w = 0;
  return __builtin_bit_cast(bf16x8, z);
}

// Fused weight prep: wTf (conv weights, encode-B-fragment order) + wF (W, B-frag order).
// wTf[kc][nt][lane][j]: element B[k'=kc*32+quad*8+j][n=nt*16+(lane&15)],
//   k'->(kk=k'/320,e=k'%320), value=(e<300)?cw[n][e][kk]:0.
// wF[kc][nt][lane][j]: element B[k=f][n=g], zero for f>=400.
__global__ void k_prep(const float* __restrict__ cw, const float* __restrict__ W,
                       u32* __restrict__ wTf, u32* __restrict__ wF){
  int idx = blockIdx.x * 256 + threadIdx.x;
  const int N1 = KC * NT * 64;
  const int N2 = KCF * NT * 64;
  if (idx < N1){
    int kc  = idx / (NT * 64);
    int rem = idx - kc * (NT * 64);
    int nt  = rem >> 6;
    int lane = rem & 63;
    int n = nt * 16 + (lane & 15);
    int quad = lane >> 4;
    u32 pack[4];
    #pragma unroll
    for (int d = 0; d < 4; d++){
      u16 h[2];
      #pragma unroll
      for (int s = 0; s < 2; s++){
        int kp = kc * 32 + quad * 8 + 2 * d + s;
        int kk = kp / 320, e = kp - kk * 320;
        float v = (e < EMBD) ? cw[(size_t)n * (EMBD * KW) + e * KW + kk] : 0.f;
        h[s] = f2b(v);
      }
      pack[d] = (u32)h[0] | ((u32)h[1] << 16);
    }
    i32x4 o; o.x = pack[0]; o.y = pack[1]; o.z = pack[2]; o.w = pack[3];
    *((i32x4*)wTf + idx) = o;
  } else if (idx < N1 + N2){
    int id2 = idx - N1;
    int kc  = id2 / (NT * 64);
    int rem = id2 - kc * (NT * 64);
    int nt  = rem >> 6;
    int lane = rem & 63;
    int n = nt * 16 + (lane & 15);
    int quad = lane >> 4;
    u32 pack[4];
    #pragma unroll
    for (int d = 0; d < 4; d++){
      u16 h[2];
      #pragma unroll
      for (int s = 0; s < 2; s++){
        int k = kc * 32 + quad * 8 + 2 * d + s;
        float v = (k < FILT) ? W[(size_t)k * FILT + n] : 0.f;
        h[s] = f2b(v);
      }
      pack[d] = (u32)h[0] | ((u32)h[1] << 16);
    }
    i32x4 o; o.x = pack[0]; o.y = pack[1]; o.z = pack[2]; o.w = pack[3];
    *((i32x4*)wF + id2) = o;
  }
}

// Embed + conv1d(pad=1) as MFMA GEMM, 32 rows x 200-col half per block.
// grid ((B*L)/32, 2). Wave w: nt = base+w+4j, j<3 (+ j=3 for half 0 wave 0).
// Staging is latency-batched: all token loads issue before the LDS zero-fill
// (overlap), then all emb float4 loads issue as one independent batch.
__global__ __launch_bounds__(256) void k_encode_mfma(const int* __restrict__ toks,
    const float* __restrict__ emb, const u32* __restrict__ wTf,
    const float* __restrict__ bias, u16* __restrict__ out, int L){
  __shared__ u16 At[34 * 328];   // 32+2 halo rows, stride 328

  const int tid  = threadIdx.x;
  const int w    = tid >> 6;
  const int lane = tid & 63;
  const int col  = lane & 15;
  const int quad = lane >> 4;
  const int half = blockIdx.y;
  const int base_nt = half ? 13 : 0;
  const bool has4 = (half == 0) && (w == 0);   // wave-uniform
  const int row0 = blockIdx.x * MT;
  const int b    = row0 / L;
  const int l0   = row0 - b * L;

  // ---- staging phase (latency-batched) ----
  int tk[10], cc[10], rws[10];
  #pragma unroll
  for (int u = 0; u < 10; u++){
    int idx = tid + 256 * u;
    tk[u] = -1; cc[u] = 0; rws[u] = 0;
    if (idx < 34 * 75){
      int r = idx / 75, c4 = idx - r * 75;
      int pos = l0 - 1 + r;
      cc[u] = c4;
      rws[u] = (r * 328 + c4 * 4) >> 1;     // u32 index into At
      if ((unsigned)pos < (unsigned)L) tk[u] = toks[b * L + pos];  // 10 indep loads
    }
  }
  for (int i = tid; i < 34 * 328 / 2; i += 256) ((u32*)At)[i] = 0u;  // overlaps tok loads
  __syncthreads();
  {
    const float4* emb4 = (const float4*)emb;
    float4 v[10];
    #pragma unroll
    for (int u = 0; u < 10; u++)
      if (tk[u] >= 0) v[u] = emb4[(size_t)tk[u] * 75 + cc[u]];      // 10 indep loads
    #pragma unroll
    for (int u = 0; u < 10; u++){
      if (tk[u] >= 0){
        u32 p0 = (u32)f2b(v[u].x) | ((u32)f2b(v[u].y) << 16);
        u32 p1 = (u32)f2b(v[u].z) | ((u32)f2b(v[u].w) << 16);
        ((u32*)At)[rws[u]]     = p0;
        ((u32*)At)[rws[u] + 1] = p1;
      }
    }
  }

  f32x4 acc[4][2];
  #pragma unroll
  for (int j = 0; j < 4; j++)
    #pragma unroll
    for (int mf = 0; mf < 2; mf++)
      acc[j][mf] = (f32x4){0.f, 0.f, 0.f, 0.f};

  __syncthreads();

  const i32x4* bbase = (const i32x4*)wTf + (size_t)(base_nt + w) * 64 + lane;
  i32x4 Bb[2][4];
  i32x4 Ab[2][2];
  {
    #pragma unroll
    for (int j = 0; j < 3; j++) Bb[0][j] = bbase[(4 * j) * 64];
    if (has4) Bb[0][3] = bbase[12 * 64];
    const int ebase0 = quad * 8;                 // kc=0: kk=0, e0=0
    Ab[0][0] = *(const i32x4*)(At + (col) * 328 + ebase0);
    Ab[0][1] = *(const i32x4*)(At + (16 + col) * 328 + ebase0);
  }
  #pragma unroll
  for (int kc = 0; kc < KC; kc++){
    const int cur = kc & 1;
    if (kc + 1 < KC){
      const i32x4* s = bbase + (size_t)(kc + 1) * (NT * 64);
      #pragma unroll
      for (int j = 0; j < 3; j++) Bb[cur ^ 1][j] = s[(4 * j) * 64];
      if (has4) Bb[cur ^ 1][3] = s[12 * 64];
      const int kk1 = (kc + 1) / 10, e01 = ((kc + 1) - kk1 * 10) * 32;
      const int ebase1 = e01 + quad * 8;
      Ab[cur ^ 1][0] = *(const i32x4*)(At + (col + kk1) * 328 + ebase1);
      Ab[cur ^ 1][1] = *(const i32x4*)(At + (16 + col + kk1) * 328 + ebase1);
    }
    bf16x8 a0 = __builtin_bit_cast(bf16x8, Ab[cur][0]);
    bf16x8 a1 = __builtin_bit_cast(bf16x8, Ab[cur][1]);
    #pragma unroll
    for (int j = 0; j < 3; j++){
      bf16x8 bf = __builtin_bit_cast(bf16x8, Bb[cur][j]);
      acc[j][0] = __builtin_amdgcn_mfma_f32_16x16x32_bf16(a0, bf, acc[j][0], 0, 0, 0);
      acc[j][1] = __builtin_amdgcn_mfma_f32_16x16x32_bf16(a1, bf, acc[j][1], 0, 0, 0);
    }
    if (has4){
      bf16x8 bf = __builtin_bit_cast(bf16x8, Bb[cur][3]);
      acc[3][0] = __builtin_amdgcn_mfma_f32_16x16x32_bf16(a0, bf, acc[3][0], 0, 0, 0);
      acc[3][1] = __builtin_amdgcn_mfma_f32_16x16x32_bf16(a1, bf, acc[3][1], 0, 0, 0);
    }
  }

  // epilogue: + bias, bf16 store. C/D: col=lane&15, row=quad*4+reg.
  #pragma unroll
  for (int j = 0; j < 4; j++){
    if (j == 3 && !has4) continue;     // wave-uniform
    int n = (base_nt + w + 4 * j) * 16 + col;
    float bv = bias[n];
    #pragma unroll
    for (int mf = 0; mf < 2; mf++){
      int rbase = row0 + mf * 16 + quad * 4;
      #pragma unroll
      for (int r = 0; r < 4; r++)
        out[(size_t)(rbase + r) * FILT + n] = f2b(acc[j][mf][r] + bv);
    }
  }
}

// T = QT * W, MFMA, no LDS, reg-double-buffered A and B, N-split in 2 halves.
__global__ __launch_bounds__(256) void k_gemmT3(const u16* __restrict__ QT,
    const u32* __restrict__ wF, u16* __restrict__ T){
  const int tid  = threadIdx.x;
  const int w    = tid >> 6;
  const int lane = tid & 63;
  const int col  = lane & 15;
  const int quad = lane >> 4;
  const int half = blockIdx.y;
  const int base_nt = half ? 13 : 0;
  const bool has4 = (half == 0) && (w == 0);
  const int row0 = blockIdx.x * MT;

  f32x4 acc[4][2];
  #pragma unroll
  for (int j = 0; j < 4; j++)
    #pragma unroll
    for (int mf = 0; mf < 2; mf++)
      acc[j][mf] = (f32x4){0.f, 0.f, 0.f, 0.f};

  const u16* arow0 = QT + (size_t)(row0 + col) * FILT;
  const u16* arow1 = QT + (size_t)(row0 + 16 + col) * FILT;
  const i32x4* bbase = (const i32x4*)wF + (size_t)(base_nt + w) * 64 + lane;

  i32x4 Ab[2][2];
  i32x4 Bb[2][4];
  {
    int off = quad * 8;
    Ab[0][0] = *(const i32x4*)(arow0 + off);
    Ab[0][1] = *(const i32x4*)(arow1 + off);
    #pragma unroll
    for (int j = 0; j < 3; j++) Bb[0][j] = bbase[(4 * j) * 64];
    if (has4) Bb[0][3] = bbase[12 * 64];
  }
  #pragma unroll
  for (int kc = 0; kc < KCF; kc++){
    const int cur = kc & 1;
    if (kc + 1 < KCF){
      int off = (kc + 1) * 32 + quad * 8;
      Ab[cur ^ 1][0] = *(const i32x4*)(arow0 + off);
      Ab[cur ^ 1][1] = *(const i32x4*)(arow1 + off);
      const i32x4* s = bbase + (size_t)(kc + 1) * (NT * 64);
      #pragma unroll
      for (int j = 0; j < 3; j++) Bb[cur ^ 1][j] = s[(4 * j) * 64];
      if (has4) Bb[cur ^ 1][3] = s[12 * 64];
    }
    bf16x8 a0 = __builtin_bit_cast(bf16x8, Ab[cur][0]);
    bf16x8 a1 = __builtin_bit_cast(bf16x8, Ab[cur][1]);
    #pragma unroll
    for (int j = 0; j < 3; j++){
      bf16x8 bf = __builtin_bit_cast(bf16x8, Bb[cur][j]);
      acc[j][0] = __builtin_amdgcn_mfma_f32_16x16x32_bf16(a0, bf, acc[j][0], 0, 0, 0);
      acc[j][1] = __builtin_amdgcn_mfma_f32_16x16x32_bf16(a1, bf, acc[j][1], 0, 0, 0);
    }
    if (has4){
      bf16x8 bf = __builtin_bit_cast(bf16x8, Bb[cur][3]);
      acc[3][0] = __builtin_amdgcn_mfma_f32_16x16x32_bf16(a0, bf, acc[3][0], 0, 0, 0);
      acc[3][1] = __builtin_amdgcn_mfma_f32_16x16x32_bf16(a1, bf, acc[3][1], 0, 0, 0);
    }
  }

  #pragma unroll
  for (int j = 0; j < 4; j++){
    if (j == 3 && !has4) continue;
    int n = (base_nt + w + 4 * j) * 16 + col;
    #pragma unroll
    for (int mf = 0; mf < 2; mf++){
      int rbase = row0 + mf * 16 + quad * 4;
      #pragma unroll
      for (int r = 0; r < 4; r++)
        T[(size_t)(rbase + r) * FILT + n] = f2b(acc[j][mf][r]);
    }
  }
}

// Scores S[q][a] = sum_g T[q][g]*AT[a][g] via MFMA; row/col maxes only.
// grid (LA/128, BB, 2): z selects 64 q-rows; wave w covers q-tile z*4+w, 8 a-tiles.
__global__ __launch_bounds__(256) void k_scores3(const u16* __restrict__ T,
    const u16* __restrict__ AT, u32* __restrict__ rowmaxE, u32* __restrict__ colmaxE){
  __shared__ float rpart[64][17];
  __shared__ float cpart[128][17];
  const int tid  = threadIdx.x;
  const int w    = tid >> 6;
  const int lane = tid & 63;
  const int col  = lane & 15;
  const int quad = lane >> 4;
  const int b    = blockIdx.y;
  const int a0   = blockIdx.x * 128;
  const int qt   = blockIdx.z * 4 + w;   // q-tile 0..7

  f32x4 acc[8];
  #pragma unroll
  for (int j = 0; j < 8; j++) acc[j] = (f32x4){0.f, 0.f, 0.f, 0.f};

  const u16* tr = T  + (size_t)(b * LQ + qt * 16 + col) * FILT;
  const u16* ar = AT + (size_t)(b * LA + a0 + col) * FILT;

  i32x4 Abuf[2], Bbuf[2][8];
  {
    int off = quad * 8;
    Abuf[0] = *(const i32x4*)(tr + off);
    #pragma unroll
    for (int j = 0; j < 8; j++)
      Bbuf[0][j] = *(const i32x4*)(ar + (size_t)(j * 16) * FILT + off);
  }
  #pragma unroll
  for (int kc = 0; kc < KCF; kc++){
    const int cur = kc & 1;
    if (kc + 1 < KCF){
      int off = (kc + 1) * 32 + quad * 8;
      Abuf[cur ^ 1] = *(const i32x4*)(tr + off);
      #pragma unroll
      for (int j = 0; j < 8; j++)
        Bbuf[cur ^ 1][j] = *(const i32x4*)(ar + (size_t)(j * 16) * FILT + off);
    }
    const bool live = (kc < 12) || (quad < 2);
    bf16x8 a0 = live ? __builtin_bit_cast(bf16x8, Abuf[cur]) : bzero();
    #pragma unroll
    for (int j = 0; j < 8; j++){
      bf16x8 bf = __builtin_bit_cast(bf16x8, Bbuf[cur][j]);
      acc[j] = __builtin_amdgcn_mfma_f32_16x16x32_bf16(a0, bf, acc[j], 0, 0, 0);
    }
  }

  #pragma unroll
  for (int r = 0; r < 4; r++){
    float m = acc[0][r];
    #pragma unroll
    for (int j = 1; j < 8; j++) m = fmaxf(m, acc[j][r]);
    rpart[w * 16 + quad * 4 + r][col] = m;
  }
  #pragma unroll
  for (int j = 0; j < 8; j++){
    float m = acc[j][0];
    #pragma unroll
    for (int r = 1; r < 4; r++) m = fmaxf(m, acc[j][r]);
    cpart[j * 16 + col][w * 4 + quad] = m;
  }
  __syncthreads();
  if (tid < 64){
    float m = rpart[tid][0];
    #pragma unroll
    for (int g = 1; g < 16; g++) m = fmaxf(m, rpart[tid][g]);
    atomicMax(&rowmaxE[b * LQ + blockIdx.z * 64 + tid], encf(m));
  } else if (tid < 192){
    int a = tid - 64;
    float m2 = cpart[a][0];
    #pragma unroll
    for (int g = 1; g < 16; g++) m2 = fmaxf(m2, cpart[a][g]);
    atomicMax(&colmaxE[b * LA + a0 + a], encf(m2));
  }
  if (tid >= 192 && tid < 256){
    int a = tid - 128;
    float m2 = cpart[a][0];
    #pragma unroll
    for (int g = 1; g < 16; g++) m2 = fmaxf(m2, cpart[a][g]);
    atomicMax(&colmaxE[b * LA + a0 + a], encf(m2));
  }
}

// Softmax weights: roq[b][128], roa[b][512] from encoded maxes. Parallel reductions.
__global__ __launch_bounds__(256) void k_soft(const u32* __restrict__ rme,
    const u32* __restrict__ cme, float* __restrict__ roq, float* __restrict__ roa){
  __shared__ float sq[128];
  __shared__ float sa[512];
  __shared__ float red[4];
  int b = blockIdx.x, tid = threadIdx.x;
  if (tid < 128) sq[tid] = tanhf(decf(rme[b * LQ + tid]));
  sa[tid]       = tanhf(decf(cme[b * LA + tid]));
  sa[tid + 256] = tanhf(decf(cme[b * LA + 256 + tid]));
  __syncthreads();
  if (tid < 64){
    float m = fmaxf(sq[tid], sq[tid + 64]);
    #pragma unroll
    for (int off = 32; off; off >>= 1) m = fmaxf(m, __shfl_down(m, off));
    if (tid == 0) red[0] = m;
  } else if (tid < 128){
    int l = tid - 64;
    float m = sa[l];
    #pragma unroll
    for (int i = 1; i < 8; i++) m = fmaxf(m, sa[l + 64 * i]);
    #pragma unroll
    for (int off = 32; off; off >>= 1) m = fmaxf(m, __shfl_down(m, off));
    if (l == 0) red[1] = m;
  }
  __syncthreads();
  float mq = red[0], ma = red[1];
  if (tid < 128) sq[tid] = __expf(sq[tid] - mq);
  sa[tid]       = __expf(sa[tid] - ma);
  sa[tid + 256] = __expf(sa[tid + 256] - ma);
  __syncthreads();
  if (tid < 64){
    float s = sq[tid] + sq[tid + 64];
    #pragma unroll
    for (int off = 32; off; off >>= 1) s += __shfl_down(s, off);
    if (tid == 0) red[2] = s;
  } else if (tid < 128){
    int l = tid - 64;
    float s = 0.f;
    #pragma unroll
    for (int i = 0; i < 8; i++) s += sa[l + 64 * i];
    #pragma unroll
    for (int off = 32; off; off >>= 1) s += __shfl_down(s, off);
    if (l == 0) red[3] = s;
  }
  __syncthreads();
  float iq = 1.f / red[2], ia = 1.f / red[3];
  if (tid < 128) roq[b * LQ + tid] = sq[tid] * iq;
  roa[b * LA + tid]       = sa[tid] * ia;
  roa[b * LA + 256 + tid] = sa[tid + 256] * ia;
}

// Segment-parallel pooling: grid (4, BB). Segment s: q in [32s,..), a in [128s,..).
__global__ __launch_bounds__(256) void k_pool(const u16* __restrict__ QT,
    const u16* __restrict__ AT, const float* __restrict__ roq, const float* __restrict__ roa,
    float* __restrict__ rqp, float* __restrict__ rap){
  __shared__ float wq[32];
  __shared__ float wa[128];
  int s = blockIdx.x, b = blockIdx.y, tid = threadIdx.x;
  if (tid < 32) wq[tid] = roq[b * LQ + s * 32 + tid];
  if (tid >= 128 && tid < 256) wa[tid - 128] = roa[b * LA + s * 128 + (tid - 128)];
  __syncthreads();
  if (tid < FILT / 2){
    const u32* qp = (const u32*)(QT + (size_t)(b * LQ + s * 32) * FILT) + tid;
    const u32* ap = (const u32*)(AT + (size_t)(b * LA + s * 128) * FILT) + tid;
    float rq0 = 0.f, rq1 = 0.f, ra0 = 0.f, ra1 = 0.f;
    for (int q = 0; q < 32; q++){
      u32 u = qp[q * (FILT / 2)];
      float wv = wq[q];
      rq0 += __uint_as_float(u << 16) * wv;
      rq1 += __uint_as_float(u & 0xFFFF0000u) * wv;
    }
    for (int a = 0; a < 128; a++){
      u32 u = ap[a * (FILT / 2)];
      float wv = wa[a];
      ra0 += __uint_as_float(u << 16) * wv;
      ra1 += __uint_as_float(u & 0xFFFF0000u) * wv;
    }
    size_t base = ((size_t)b * 4 + s) * FILT + 2 * tid;
    rqp[base] = rq0; rqp[base + 1] = rq1;
    rap[base] = ra0; rap[base + 1] = ra1;
  }
}

// Reduce 4 partials, cosine similarity. grid (BB), 256 threads.
__global__ __launch_bounds__(256) void k_cos(const float* __restrict__ rqp,
    const float* __restrict__ rap, float* __restrict__ outp){
  __shared__ float rd[4], r1[4], r2[4];
  int b = blockIdx.x, tid = threadIdx.x;
  int lane = tid & 63, w = tid >> 6;
  float d = 0.f, n1 = 0.f, n2 = 0.f;
  for (int f = tid; f < FILT; f += 256){
    size_t base = (size_t)b * 4 * FILT + f;
    float rq = rqp[base] + rqp[base + FILT] + rqp[base + 2 * FILT] + rqp[base + 3 * FILT];
    float ra = rap[base] + rap[base + FILT] + rap[base + 2 * FILT] + rap[base + 3 * FILT];
    d += rq * ra; n1 += rq * rq; n2 += ra * ra;
  }
  #pragma unroll
  for (int off = 32; off; off >>= 1){
    d  += __shfl_down(d, off);
    n1 += __shfl_down(n1, off);
    n2 += __shfl_down(n2, off);
  }
  if (lane == 0){ rd[w] = d; r1[w] = n1; r2[w] = n2; }
  __syncthreads();
  if (tid == 0){
    float D  = rd[0] + rd[1] + rd[2] + rd[3];
    float N1 = r1[0] + r1[1] + r1[2] + r1[3];
    float N2 = r2[0] + r2[1] + r2[2] + r2[3];
    outp[b] = D / (fmaxf(sqrtf(N1), 1e-8f) * fmaxf(sqrtf(N2), 1e-8f));
  }
}

extern "C" void kernel_launch(void* const* d_in, const int* in_sizes, int n_in,
                              void* d_out, int out_size, void* d_ws, size_t ws_size,
                              hipStream_t stream){
  const int*   qtok = (const int*)d_in[0];
  const int*   atok = (const int*)d_in[1];
  const float* emb  = (const float*)d_in[2];
  const float* cw   = (const float*)d_in[3];
  const float* cb   = (const float*)d_in[4];
  const float* W    = (const float*)d_in[5];
  float* outp = (float*)d_out;

  char* ws = (char*)d_ws;
  size_t off = 0;
  auto alloc = [&](size_t bytes) -> char* {
    char* p = ws + off;
    off = (off + bytes + 255) & ~(size_t)255;
    return p;
  };
  u32*   wTf = (u32*)alloc((size_t)KC * NT * 64 * 16);   // 768 KB
  u32*   wF  = (u32*)alloc((size_t)KCF * NT * 64 * 16);  // 333 KB
  u16*   QT  = (u16*)alloc((size_t)BB * LQ * FILT * 2);  // 13.1 MB
  u16*   AT  = (u16*)alloc((size_t)BB * LA * FILT * 2);  // 52.4 MB
  u16*   T   = (u16*)alloc((size_t)BB * LQ * FILT * 2);  // 13.1 MB
  u32*   rme = (u32*)alloc((size_t)BB * LQ * 4);         // adjacent to cme
  u32*   cme = (u32*)alloc((size_t)BB * LA * 4);
  float* roq = (float*)alloc((size_t)BB * LQ * 4);
  float* roa = (float*)alloc((size_t)BB * LA * 4);
  float* rqp = (float*)alloc((size_t)BB * 4 * FILT * 4); // 819 KB
  float* rap = (float*)alloc((size_t)BB * 4 * FILT * 4); // 819 KB

  // rme and cme are contiguous (both sizes are multiples of 256B): one memset.
  hipMemsetAsync(rme, 0, (size_t)BB * LQ * 4 + (size_t)BB * LA * 4, stream);

  const int NPREP = KC * NT * 64 + KCF * NT * 64;
  k_prep<<<dim3((NPREP + 255) / 256), 256, 0, stream>>>(cw, W, wTf, wF);
  k_encode_mfma<<<dim3(BB * LQ / MT, 2), 256, 0, stream>>>(qtok, emb, wTf, cb, QT, LQ);
  k_encode_mfma<<<dim3(BB * LA / MT, 2), 256, 0, stream>>>(atok, emb, wTf, cb, AT, LA);
  k_gemmT3<<<dim3(BB * LQ / MT, 2), 256, 0, stream>>>(QT, wF, T);
  k_scores3<<<dim3(LA / 128, BB, 2), 256, 0, stream>>>(T, AT, rme, cme);
  k_soft<<<dim3(BB), 256, 0, stream>>>(rme, cme, roq, roa);
  k_pool<<<dim3(4, BB), 256, 0, stream>>>(QT, AT, roq, roa, rqp, rap);
  k_cos<<<dim3(BB), 256, 0, stream>>>(rqp, rap, outp);
}